// Round 14
// baseline (314.195 us; speedup 1.0000x reference)
//
#include <hip/hip_runtime.h>
#include <hip/hip_fp16.h>

#define HIST 50

typedef __fp16 hf;
typedef __fp16 hf2 __attribute__((ext_vector_type(2)));
typedef __fp16 h8  __attribute__((ext_vector_type(8)));
typedef float  f4  __attribute__((ext_vector_type(4)));

union U32H2 { unsigned u; hf2 h; };
__device__ __forceinline__ unsigned h2u(hf2 h){ U32H2 c; c.h=h; return c.u; }
__device__ __forceinline__ hf2 pkrtz(float a,float b){ return __builtin_amdgcn_cvt_pkrtz(a,b); }

__device__ __forceinline__ h8 mk8(hf2 a, hf2 b, hf2 c, hf2 d){
    h8 r; r[0]=a[0]; r[1]=a[1]; r[2]=b[0]; r[3]=b[1]; r[4]=c[0]; r[5]=c[1]; r[6]=d[0]; r[7]=d[1]; return r;
}
__device__ __forceinline__ h8 ldfrag(const float* W, long row, int kb){
    const float4 v0 = *(const float4*)(W + row + kb);
    const float4 v1 = *(const float4*)(W + row + kb + 4);
    return mk8(pkrtz(v0.x,v0.y), pkrtz(v0.z,v0.w), pkrtz(v1.x,v1.y), pkrtz(v1.z,v1.w));
}
__device__ __forceinline__ f4 mfma16(h8 a, h8 b, f4 c){
    return __builtin_amdgcn_mfma_f32_16x16x32_f16(a,b,c,0,0,0);
}
__device__ __forceinline__ f4 relu4(f4 v){
    v[0]=fmaxf(v[0],0.f); v[1]=fmaxf(v[1],0.f); v[2]=fmaxf(v[2],0.f); v[3]=fmaxf(v[3],0.f); return v;
}

// store C-layout tile (acc[nt]: col=16nt+(lane&15), rows (lane>>4)*4+r) as swizzled f16 [16][64]
__device__ __forceinline__ void store_ct(unsigned short* base, const f4* acc, int lane){
    const int m0    = (lane>>4)*4;
    const int ceven = lane & 14;
    const bool odd  = lane & 1;
    #pragma unroll
    for (int nt = 0; nt < 4; ++nt){
        const int c0 = 16*nt + ceven;
        #pragma unroll
        for (int r = 0; r < 4; ++r){
            const float mine = acc[nt][r];
            const float oth  = __shfl_xor(mine, 1);
            if (!odd){
                const int m    = m0 + r;
                const int gp   = (c0 >> 3) ^ (m & 7);
                const int byte = m*128 + gp*16 + ((2*c0) & 15);
                *(unsigned*)((char*)base + byte) = h2u(pkrtz(mine, oth));
            }
        }
    }
}
__device__ __forceinline__ h8 read_af(const unsigned short* base, int lane, int kt){
    const int row  = lane & 15;
    const int gp   = (4*kt + (lane>>4)) ^ (row & 7);
    const int byte = row*128 + gp*16;
    return *(const h8*)((const char*)base + byte);
}

__global__ __launch_bounds__(64, 1)   // 512-reg unified budget; weights resident, 2 node-streams per wave
void ue_mfma2(const int* __restrict__ nodes, const int* __restrict__ hitems,
              const int* __restrict__ hrat, const int* __restrict__ hlen,
              const float* __restrict__ u2e, const float* __restrict__ i2e,
              const float* __restrict__ r2e,
              const float* __restrict__ w1w, const float* __restrict__ w1b,
              const float* __restrict__ w2w, const float* __restrict__ w2b,
              const float* __restrict__ a1w, const float* __restrict__ a1b,
              const float* __restrict__ a2w, const float* __restrict__ a2b,
              const float* __restrict__ a3w, const float* __restrict__ a3b,
              float* __restrict__ out, int n_nodes)
{
    const int lane = threadIdx.x;
    const int nidx = lane & 15;
    const int kgrp = lane >> 4;

    __shared__ __align__(16) unsigned short xfer[2][16*64];
    __shared__ __align__(16) unsigned short o_all[2][4*16*64];
    __shared__ __align__(16) float uax[2][64];
    __shared__ __align__(16) float ubias_lds[2][64];
    __shared__ __align__(16) int   ih[2][HIST];
    __shared__ __align__(16) int   rh[2][HIST];
    __shared__ __align__(16) float sc[2][64];
    __shared__ __align__(16) float attv[2][64];

    // ---- weight fragments (lane: n=16nt+nidx, k=32kt+8*kgrp+i) ----
    h8 W1f[4][4], W2f[2][4], A1f[2][4], A2f[2][4];
    #pragma unroll
    for (int nt = 0; nt < 4; ++nt){
        const long row128 = (long)(16*nt + nidx) * 128;
        const long row64  = (long)(16*nt + nidx) * 64;
        #pragma unroll
        for (int kt = 0; kt < 4; ++kt)
            W1f[kt][nt] = ldfrag(w1w, row128, 32*kt + 8*kgrp);
        #pragma unroll
        for (int kt = 0; kt < 2; ++kt){
            W2f[kt][nt] = ldfrag(w2w, row64,  32*kt + 8*kgrp);
            A1f[kt][nt] = ldfrag(a1w, row128, 32*kt + 8*kgrp);
            A2f[kt][nt] = ldfrag(a2w, row64,  32*kt + 8*kgrp);
        }
    }
    float b1c[4], b2c[4], ab2c[4], a3c[4];
    #pragma unroll
    for (int nt = 0; nt < 4; ++nt){
        b1c[nt]  = w1b[16*nt + nidx];
        b2c[nt]  = w2b[16*nt + nidx];
        ab2c[nt] = a2b[16*nt + nidx];
        a3c[nt]  = a3w[16*nt + nidx];
    }
    const float ab1r = a1b[lane];

    const int half = (n_nodes + 1) >> 1;
    for (int b = blockIdx.x; b < half; b += gridDim.x) {
        const int  nn0 = b,       nn1 = b + half;
        const bool a0  = true;    const bool a1 = (nn1 < n_nodes);
        __syncthreads();   // drain previous iteration's LDS reads

        int hls[2], tiles[2];
        {   // per-stream node staging
            const int node0 = nodes[nn0];
            hls[0] = hlen[nn0];
            uax[0][lane] = u2e[(long)node0 * 64 + lane];
            if (lane < HIST){ ih[0][lane] = hitems[nn0*HIST+lane]; rh[0][lane] = hrat[nn0*HIST+lane]; }
            if (a1) {
                const int node1 = nodes[nn1];
                hls[1] = hlen[nn1];
                uax[1][lane] = u2e[(long)node1 * 64 + lane];
                if (lane < HIST){ ih[1][lane] = hitems[nn1*HIST+lane]; rh[1][lane] = hrat[nn1*HIST+lane]; }
            } else hls[1] = 0;
        }
        tiles[0] = (hls[0] + 15) >> 4;
        tiles[1] = (hls[1] + 15) >> 4;
        __syncthreads();

        // ---- ubias per stream ----
        #pragma unroll
        for (int s = 0; s < 2; ++s){
            if (s == 0 || a1) {
                float u0 = ab1r, u1 = 0.f, u2 = 0.f, u3 = 0.f;
                #pragma unroll
                for (int t = 0; t < 16; ++t) {
                    const float4 v = *(const float4*)(a1w + (long)lane*128 + 64 + 4*t);
                    u0 = fmaf(v.x, uax[s][4*t+0], u0);
                    u1 = fmaf(v.y, uax[s][4*t+1], u1);
                    u2 = fmaf(v.z, uax[s][4*t+2], u2);
                    u3 = fmaf(v.w, uax[s][4*t+3], u3);
                }
                ubias_lds[s][lane] = (u0 + u1) + (u2 + u3);
            }
        }
        __syncthreads();
        float ubc[2][4];
        #pragma unroll
        for (int s = 0; s < 2; ++s)
            #pragma unroll
            for (int nt = 0; nt < 4; ++nt) ubc[s][nt] = ubias_lds[s][16*nt + nidx];

        const int tmax = tiles[0] > tiles[1] ? tiles[0] : tiles[1];
        for (int t = 0; t < tmax; ++t) {
            // ---- stage 0: issue BOTH streams' gathers first (latency overlap) ----
            h8 Xf[2][4];
            #pragma unroll
            for (int s = 0; s < 2; ++s){
                if (t < tiles[s]){
                    int p = t*16 + nidx; if (p >= hls[s]) p = hls[s] - 1;
                    const long irow = (long)ih[s][p] * 64;
                    const long rrow = (long)rh[s][p] * 64;
                    const int  kb   = 8 * kgrp;
                    Xf[s][0] = ldfrag(i2e, irow, kb);
                    Xf[s][1] = ldfrag(i2e, irow, 32 + kb);
                    Xf[s][2] = ldfrag(r2e, rrow, kb);
                    Xf[s][3] = ldfrag(r2e, rrow, 32 + kb);
                }
            }
            // ---- stage 1: layer 1 ----
            #pragma unroll
            for (int s = 0; s < 2; ++s){
                if (t < tiles[s]){
                    f4 acc[4];
                    #pragma unroll
                    for (int nt = 0; nt < 4; ++nt){
                        f4 c = { b1c[nt], b1c[nt], b1c[nt], b1c[nt] };
                        #pragma unroll
                        for (int kt = 0; kt < 4; ++kt) c = mfma16(Xf[s][kt], W1f[kt][nt], c);
                        acc[nt] = relu4(c);
                    }
                    store_ct(xfer[s], acc, lane);
                }
            }
            __syncthreads();
            // ---- stage 2: layer 2 -> o ----
            #pragma unroll
            for (int s = 0; s < 2; ++s){
                if (t < tiles[s]){
                    const h8 yf0 = read_af(xfer[s], lane, 0), yf1 = read_af(xfer[s], lane, 1);
                    f4 acc[4];
                    #pragma unroll
                    for (int nt = 0; nt < 4; ++nt){
                        f4 c = { b2c[nt], b2c[nt], b2c[nt], b2c[nt] };
                        c = mfma16(yf0, W2f[0][nt], c);
                        c = mfma16(yf1, W2f[1][nt], c);
                        acc[nt] = relu4(c);
                    }
                    store_ct(o_all[s] + t*1024, acc, lane);
                }
            }
            __syncthreads();
            // ---- stage 3: att layer 1 (u folded in ubias) ----
            #pragma unroll
            for (int s = 0; s < 2; ++s){
                if (t < tiles[s]){
                    const h8 of0 = read_af(o_all[s] + t*1024, lane, 0), of1 = read_af(o_all[s] + t*1024, lane, 1);
                    f4 acc[4];
                    #pragma unroll
                    for (int nt = 0; nt < 4; ++nt){
                        f4 c = { ubc[s][nt], ubc[s][nt], ubc[s][nt], ubc[s][nt] };
                        c = mfma16(of0, A1f[0][nt], c);
                        c = mfma16(of1, A1f[1][nt], c);
                        acc[nt] = relu4(c);
                    }
                    store_ct(xfer[s], acc, lane);
                }
            }
            __syncthreads();
            // ---- stage 4: att layer 2 + score ----
            #pragma unroll
            for (int s = 0; s < 2; ++s){
                if (t < tiles[s]){
                    const h8 af0 = read_af(xfer[s], lane, 0), af1 = read_af(xfer[s], lane, 1);
                    f4 acc[4];
                    #pragma unroll
                    for (int nt = 0; nt < 4; ++nt){
                        f4 c = { ab2c[nt], ab2c[nt], ab2c[nt], ab2c[nt] };
                        c = mfma16(af0, A2f[0][nt], c);
                        c = mfma16(af1, A2f[1][nt], c);
                        acc[nt] = relu4(c);
                    }
                    f4 sv = { 0.f, 0.f, 0.f, 0.f };
                    #pragma unroll
                    for (int nt = 0; nt < 4; ++nt){
                        sv[0] = fmaf(acc[nt][0], a3c[nt], sv[0]);
                        sv[1] = fmaf(acc[nt][1], a3c[nt], sv[1]);
                        sv[2] = fmaf(acc[nt][2], a3c[nt], sv[2]);
                        sv[3] = fmaf(acc[nt][3], a3c[nt], sv[3]);
                    }
                    #pragma unroll
                    for (int off = 1; off <= 8; off <<= 1){
                        sv[0] += __shfl_xor(sv[0], off);
                        sv[1] += __shfl_xor(sv[1], off);
                        sv[2] += __shfl_xor(sv[2], off);
                        sv[3] += __shfl_xor(sv[3], off);
                    }
                    if (nidx == 0){
                        const int m0 = kgrp * 4;
                        sc[s][t*16 + m0 + 0] = sv[0];
                        sc[s][t*16 + m0 + 1] = sv[1];
                        sc[s][t*16 + m0 + 2] = sv[2];
                        sc[s][t*16 + m0 + 3] = sv[3];
                    }
                }
            }
            __syncthreads();
        }

        // ---- per-stream softmax ----
        const float NEG_INF = -__builtin_inff();
        #pragma unroll
        for (int s = 0; s < 2; ++s){
            if (s == 0 || a1){
                const float sv = (lane < hls[s]) ? sc[s][lane] : NEG_INF;
                float m = sv;
                #pragma unroll
                for (int off = 32; off; off >>= 1) m = fmaxf(m, __shfl_xor(m, off));
                const float e = (lane < hls[s]) ? expf(sv - m) : 0.f;
                float se = e;
                #pragma unroll
                for (int off = 32; off; off >>= 1) se += __shfl_xor(se, off);
                attv[s][lane] = e / se;
            }
        }
        __syncthreads();

        // ---- per-stream weighted sum ----
        const int gpj = lane >> 3;
        const int oj  = (2*lane) & 15;
        #pragma unroll
        for (int s = 0; s < 2; ++s){
            if (s == 0 || a1){
                float part = 0.f;
                for (int l = 0; l < hls[s]; ++l){
                    const float al  = attv[s][l];
                    const int   row = l & 15;
                    const int   byte = (l >> 4)*2048 + row*128 + ((gpj ^ (row & 7))*16) + oj;
                    const hf hv = *(const hf*)((const char*)o_all[s] + byte);
                    part = fmaf(al, (float)hv, part);
                }
                out[(long)(s == 0 ? nn0 : nn1) * 64 + lane] = part;
            }
        }
    }
}

extern "C" void kernel_launch(void* const* d_in, const int* in_sizes, int n_in,
                              void* d_out, int out_size, void* d_ws, size_t ws_size,
                              hipStream_t stream) {
    const int*   nodes  = (const int*)d_in[0];
    const int*   hitems = (const int*)d_in[1];
    const int*   hrat   = (const int*)d_in[2];
    const int*   hlenp  = (const int*)d_in[3];
    const float* u2e    = (const float*)d_in[4];
    const float* i2e    = (const float*)d_in[5];
    const float* r2e    = (const float*)d_in[6];
    const float* w1w    = (const float*)d_in[7];
    const float* w1b    = (const float*)d_in[8];
    const float* w2w    = (const float*)d_in[9];
    const float* w2b    = (const float*)d_in[10];
    const float* a1w    = (const float*)d_in[11];
    const float* a1b    = (const float*)d_in[12];
    const float* a2w    = (const float*)d_in[13];
    const float* a2b    = (const float*)d_in[14];
    const float* a3w    = (const float*)d_in[15];
    const float* a3b    = (const float*)d_in[16];
    float* out = (float*)d_out;

    const int n_nodes = in_sizes[0];
    const int blocks  = 8192;   // wave b handles nodes b and b+8192
    ue_mfma2<<<dim3(blocks), dim3(64), 0, stream>>>(
        nodes, hitems, hrat, hlenp, u2e, i2e, r2e,
        w1w, w1b, w2w, w2b, a1w, a1b, a2w, a2b, a3w, a3b,
        out, n_nodes);
}

// Round 15
// 205.488 us; speedup vs baseline: 1.5290x; 1.5290x over previous
//
#include <hip/hip_runtime.h>
#include <hip/hip_fp16.h>

#define HIST 50
#define WPB 8   // waves per block (512 threads)

typedef __fp16 hf;
typedef __fp16 hf2 __attribute__((ext_vector_type(2)));
typedef __fp16 h8  __attribute__((ext_vector_type(8)));
typedef float  f4  __attribute__((ext_vector_type(4)));

union U32H2 { unsigned u; hf2 h; };
__device__ __forceinline__ unsigned h2u(hf2 h){ U32H2 c; c.h=h; return c.u; }
__device__ __forceinline__ hf2 pkrtz(float a,float b){ return __builtin_amdgcn_cvt_pkrtz(a,b); }

__device__ __forceinline__ h8 mk8(hf2 a, hf2 b, hf2 c, hf2 d){
    h8 r; r[0]=a[0]; r[1]=a[1]; r[2]=b[0]; r[3]=b[1]; r[4]=c[0]; r[5]=c[1]; r[6]=d[0]; r[7]=d[1]; return r;
}
// 8 consecutive f32 at W[row + kb .. +7] -> f16x8 fragment
__device__ __forceinline__ h8 ldfrag(const float* W, long row, int kb){
    const float4 v0 = *(const float4*)(W + row + kb);
    const float4 v1 = *(const float4*)(W + row + kb + 4);
    return mk8(pkrtz(v0.x,v0.y), pkrtz(v0.z,v0.w), pkrtz(v1.x,v1.y), pkrtz(v1.z,v1.w));
}
__device__ __forceinline__ f4 mfma16(h8 a, h8 b, f4 c){
    return __builtin_amdgcn_mfma_f32_16x16x32_f16(a,b,c,0,0,0);
}
__device__ __forceinline__ f4 relu4(f4 v){
    v[0]=fmaxf(v[0],0.f); v[1]=fmaxf(v[1],0.f); v[2]=fmaxf(v[2],0.f); v[3]=fmaxf(v[3],0.f); return v;
}
// intra-wave LDS write->read fence (in-order DS pipe + stop compiler reordering; rule #18)
__device__ __forceinline__ void wsync(){
    asm volatile("s_waitcnt lgkmcnt(0)" ::: "memory");
    __builtin_amdgcn_sched_barrier(0);
}

// store C-layout tile (acc[nt]: col=16nt+(lane&15), rows (lane>>4)*4+r) as swizzled f16 [16][64]
__device__ __forceinline__ void store_ct(unsigned short* base, const f4* acc, int lane){
    const int m0    = (lane>>4)*4;
    const int ceven = lane & 14;
    const bool odd  = lane & 1;
    #pragma unroll
    for (int nt = 0; nt < 4; ++nt){
        const int c0 = 16*nt + ceven;
        #pragma unroll
        for (int r = 0; r < 4; ++r){
            const float mine = acc[nt][r];
            const float oth  = __shfl_xor(mine, 1);
            if (!odd){
                const int m    = m0 + r;
                const int gp   = (c0 >> 3) ^ (m & 7);
                const int byte = m*128 + gp*16 + ((2*c0) & 15);
                *(unsigned*)((char*)base + byte) = h2u(pkrtz(mine, oth));
            }
        }
    }
}
__device__ __forceinline__ h8 read_af(const unsigned short* base, int lane, int kt){
    const int row  = lane & 15;
    const int gp   = (4*kt + (lane>>4)) ^ (row & 7);
    const int byte = row*128 + gp*16;
    return *(const h8*)((const char*)base + byte);
}

__global__ __launch_bounds__(512, 4)   // 8 waves/block; 2 blocks/CU (LDS) -> 16 waves/CU; VGPR cap 128
void ue_v3(const int* __restrict__ nodes, const int* __restrict__ hitems,
           const int* __restrict__ hrat, const int* __restrict__ hlen,
           const float* __restrict__ u2e, const float* __restrict__ i2e,
           const float* __restrict__ r2e,
           const float* __restrict__ w1w, const float* __restrict__ w1b,
           const float* __restrict__ w2w, const float* __restrict__ w2b,
           const float* __restrict__ a1w, const float* __restrict__ a1b,
           const float* __restrict__ a2w, const float* __restrict__ a2b,
           const float* __restrict__ a3w, const float* __restrict__ a3b,
           float* __restrict__ out, int n_nodes)
{
    const int tid  = threadIdx.x;
    const int lane = tid & 63;
    const int wid  = tid >> 6;
    const int nidx = lane & 15;
    const int kgrp = lane >> 4;

    // weight fragments: 40 blocks (W1:0-15, W2:16-23, A1o:24-31, A2:32-39), each 64 lanes x 16B
    __shared__ __align__(16) unsigned short wlds[40*512];
    __shared__ __align__(16) unsigned short xfer[WPB][16*64];   // per-wave transpose buffer
    __shared__ __align__(16) float uax[WPB][64];
    __shared__ __align__(16) float ubl[WPB][64];
    __shared__ int ihs[WPB][HIST];
    __shared__ int rhs[WPB][HIST];

    // ---- cooperative weight staging (once per block) ----
    for (int f = tid; f < 40*64; f += blockDim.x) {
        const int blk = f >> 6, l = f & 63;
        const float* src; int ld, kt, nt;
        if (blk < 16)      { kt = blk>>2;      nt = blk&3;      src = w1w; ld = 128; }
        else if (blk < 24) { kt = (blk-16)>>2; nt = (blk-16)&3; src = w2w; ld = 64;  }
        else if (blk < 32) { kt = (blk-24)>>2; nt = (blk-24)&3; src = a1w; ld = 128; }
        else               { kt = (blk-32)>>2; nt = (blk-32)&3; src = a2w; ld = 64;  }
        const int nrow = 16*nt + (l & 15);
        const int kcol = 32*kt + 8*(l >> 4);
        *(h8*)&wlds[blk*512 + l*8] = ldfrag(src, (long)nrow*ld, kcol);
    }
    __syncthreads();   // the ONLY block-wide barrier

    #define BF(base,kt,nt) (*(const h8*)&wlds[((base)+(kt)*4+(nt))*512 + lane*8])

    float b1c[4], b2c[4], ab2c[4], a3c[4];
    #pragma unroll
    for (int nt = 0; nt < 4; ++nt){
        b1c[nt]  = w1b[16*nt + nidx];
        b2c[nt]  = w2b[16*nt + nidx];
        ab2c[nt] = a2b[16*nt + nidx];
        a3c[nt]  = a3w[16*nt + nidx];
    }
    const float ab1r = a1b[lane];
    const float NEG_INF = -__builtin_inff();

    for (int n = blockIdx.x * WPB + wid; n < n_nodes; n += gridDim.x * WPB) {
        const int node = nodes[n];
        const int hl   = hlen[n];

        uax[wid][lane] = u2e[(long)node * 64 + lane];
        if (lane < HIST){ ihs[wid][lane] = hitems[n*HIST+lane]; rhs[wid][lane] = hrat[n*HIST+lane]; }
        wsync();

        // ubias_j = ab1_j + sum_k u_k * A1[j][64+k]  (u-half of att1, folded per node)
        float u0 = ab1r, u1 = 0.f, u2 = 0.f, u3 = 0.f;
        #pragma unroll
        for (int t = 0; t < 16; ++t) {
            const float4 v = *(const float4*)(a1w + (long)lane*128 + 64 + 4*t);
            u0 = fmaf(v.x, uax[wid][4*t+0], u0);
            u1 = fmaf(v.y, uax[wid][4*t+1], u1);
            u2 = fmaf(v.z, uax[wid][4*t+2], u2);
            u3 = fmaf(v.w, uax[wid][4*t+3], u3);
        }
        ubl[wid][lane] = (u0 + u1) + (u2 + u3);
        wsync();
        float ubc[4];
        #pragma unroll
        for (int nt = 0; nt < 4; ++nt) ubc[nt] = ubl[wid][16*nt + nidx];

        // online softmax state
        float m_run = NEG_INF, run_sum = 0.f;
        float outacc[4] = {0.f, 0.f, 0.f, 0.f};

        const int tiles = (hl + 15) >> 4;
        for (int t = 0; t < tiles; ++t) {
            int p = t*16 + nidx; if (p >= hl) p = hl - 1;   // clamp pad rows (masked below)
            const long irow = (long)ihs[wid][p] * 64;
            const long rrow = (long)rhs[wid][p] * 64;
            const int  kb   = 8 * kgrp;
            const h8 Xf0 = ldfrag(i2e, irow, kb);
            const h8 Xf1 = ldfrag(i2e, irow, 32 + kb);
            const h8 Xf2 = ldfrag(r2e, rrow, kb);
            const h8 Xf3 = ldfrag(r2e, rrow, 32 + kb);

            // layer 1: [16x128] @ [128x64]
            f4 acc[4];
            #pragma unroll
            for (int nt = 0; nt < 4; ++nt){
                f4 c = { b1c[nt], b1c[nt], b1c[nt], b1c[nt] };
                c = mfma16(Xf0, BF(0,0,nt), c);
                c = mfma16(Xf1, BF(0,1,nt), c);
                c = mfma16(Xf2, BF(0,2,nt), c);
                c = mfma16(Xf3, BF(0,3,nt), c);
                acc[nt] = relu4(c);
            }
            store_ct(xfer[wid], acc, lane);
            wsync();
            const h8 yf0 = read_af(xfer[wid], lane, 0), yf1 = read_af(xfer[wid], lane, 1);

            // layer 2 -> o (stays in f32 C-layout regs)
            f4 occ[4];
            #pragma unroll
            for (int nt = 0; nt < 4; ++nt){
                f4 c = { b2c[nt], b2c[nt], b2c[nt], b2c[nt] };
                c = mfma16(yf0, BF(16,0,nt), c);
                c = mfma16(yf1, BF(16,1,nt), c);
                occ[nt] = relu4(c);
            }
            store_ct(xfer[wid], occ, lane);
            wsync();
            const h8 of0 = read_af(xfer[wid], lane, 0), of1 = read_af(xfer[wid], lane, 1);

            // att layer 1 (o-half; u folded in ubias)
            #pragma unroll
            for (int nt = 0; nt < 4; ++nt){
                f4 c = { ubc[nt], ubc[nt], ubc[nt], ubc[nt] };
                c = mfma16(of0, BF(24,0,nt), c);
                c = mfma16(of1, BF(24,1,nt), c);
                acc[nt] = relu4(c);
            }
            store_ct(xfer[wid], acc, lane);
            wsync();
            const h8 af0 = read_af(xfer[wid], lane, 0), af1 = read_af(xfer[wid], lane, 1);

            // att layer 2
            #pragma unroll
            for (int nt = 0; nt < 4; ++nt){
                f4 c = { ab2c[nt], ab2c[nt], ab2c[nt], ab2c[nt] };
                c = mfma16(af0, BF(32,0,nt), c);
                c = mfma16(af1, BF(32,1,nt), c);
                acc[nt] = relu4(c);
            }

            // scores per row (att3 bias dropped: softmax shift-invariant)
            float sv0 = 0.f, sv1 = 0.f, sv2 = 0.f, sv3 = 0.f;
            #pragma unroll
            for (int nt = 0; nt < 4; ++nt){
                sv0 = fmaf(acc[nt][0], a3c[nt], sv0);
                sv1 = fmaf(acc[nt][1], a3c[nt], sv1);
                sv2 = fmaf(acc[nt][2], a3c[nt], sv2);
                sv3 = fmaf(acc[nt][3], a3c[nt], sv3);
            }
            #pragma unroll
            for (int off = 1; off <= 8; off <<= 1){
                sv0 += __shfl_xor(sv0, off);
                sv1 += __shfl_xor(sv1, off);
                sv2 += __shfl_xor(sv2, off);
                sv3 += __shfl_xor(sv3, off);
            }

            // online softmax update over this tile's 16 rows
            const int base = t*16 + kgrp*4;
            const bool v0 = base+0 < hl, v1 = base+1 < hl, v2 = base+2 < hl, v3 = base+3 < hl;
            float tmax = fmaxf(fmaxf(v0 ? sv0 : NEG_INF, v1 ? sv1 : NEG_INF),
                               fmaxf(v2 ? sv2 : NEG_INF, v3 ? sv3 : NEG_INF));
            tmax = fmaxf(tmax, __shfl_xor(tmax, 16));
            tmax = fmaxf(tmax, __shfl_xor(tmax, 32));
            const float m_new = fmaxf(m_run, tmax);
            const float fs = expf(m_run - m_new);    // 0 on first tile (m_run=-inf)
            const float w0 = v0 ? expf(sv0 - m_new) : 0.f;
            const float w1 = v1 ? expf(sv1 - m_new) : 0.f;
            const float w2 = v2 ? expf(sv2 - m_new) : 0.f;
            const float w3 = v3 ? expf(sv3 - m_new) : 0.f;
            float wsum = (w0 + w1) + (w2 + w3);
            float cp[4];
            #pragma unroll
            for (int nt = 0; nt < 4; ++nt)
                cp[nt] = ((w0*occ[nt][0] + w1*occ[nt][1]) + (w2*occ[nt][2] + w3*occ[nt][3]));
            wsum += __shfl_xor(wsum, 16); wsum += __shfl_xor(wsum, 32);
            #pragma unroll
            for (int nt = 0; nt < 4; ++nt){
                cp[nt] += __shfl_xor(cp[nt], 16);
                cp[nt] += __shfl_xor(cp[nt], 32);
            }
            run_sum = run_sum * fs + wsum;
            #pragma unroll
            for (int nt = 0; nt < 4; ++nt) outacc[nt] = outacc[nt] * fs + cp[nt];
            m_run = m_new;
        }

        const float inv = 1.f / run_sum;
        if (kgrp == 0){
            #pragma unroll
            for (int nt = 0; nt < 4; ++nt)
                out[(long)n * 64 + 16*nt + nidx] = outacc[nt] * inv;
        }
    }
    #undef BF
}

extern "C" void kernel_launch(void* const* d_in, const int* in_sizes, int n_in,
                              void* d_out, int out_size, void* d_ws, size_t ws_size,
                              hipStream_t stream) {
    const int*   nodes  = (const int*)d_in[0];
    const int*   hitems = (const int*)d_in[1];
    const int*   hrat   = (const int*)d_in[2];
    const int*   hlenp  = (const int*)d_in[3];
    const float* u2e    = (const float*)d_in[4];
    const float* i2e    = (const float*)d_in[5];
    const float* r2e    = (const float*)d_in[6];
    const float* w1w    = (const float*)d_in[7];
    const float* w1b    = (const float*)d_in[8];
    const float* w2w    = (const float*)d_in[9];
    const float* w2b    = (const float*)d_in[10];
    const float* a1w    = (const float*)d_in[11];
    const float* a1b    = (const float*)d_in[12];
    const float* a2w    = (const float*)d_in[13];
    const float* a2b    = (const float*)d_in[14];
    const float* a3w    = (const float*)d_in[15];
    const float* a3b    = (const float*)d_in[16];
    float* out = (float*)d_out;

    const int n_nodes = in_sizes[0];
    const int blocks  = 2048;   // 8 waves each: one node per wave, grid covers 16384 exactly
    ue_v3<<<dim3(blocks), dim3(512), 0, stream>>>(
        nodes, hitems, hrat, hlenp, u2e, i2e, r2e,
        w1w, w1b, w2w, w2b, a1w, a1b, a2w, a2b, a3w, a3b,
        out, n_nodes);
}

// Round 16
// 194.821 us; speedup vs baseline: 1.6127x; 1.0548x over previous
//
#include <hip/hip_runtime.h>
#include <hip/hip_fp16.h>

#define HIST 50
#define WPB 8   // waves per block (512 threads)

typedef __fp16 hf;
typedef __fp16 hf2 __attribute__((ext_vector_type(2)));
typedef __fp16 h8  __attribute__((ext_vector_type(8)));
typedef float  f4  __attribute__((ext_vector_type(4)));

union U32H2 { unsigned u; hf2 h; };
__device__ __forceinline__ unsigned h2u(hf2 h){ U32H2 c; c.h=h; return c.u; }
__device__ __forceinline__ hf2 pkrtz(float a,float b){ return __builtin_amdgcn_cvt_pkrtz(a,b); }

__device__ __forceinline__ h8 mk8(hf2 a, hf2 b, hf2 c, hf2 d){
    h8 r; r[0]=a[0]; r[1]=a[1]; r[2]=b[0]; r[3]=b[1]; r[4]=c[0]; r[5]=c[1]; r[6]=d[0]; r[7]=d[1]; return r;
}
// 8 consecutive f32 at W[row + kb .. +7] -> f16x8 fragment
__device__ __forceinline__ h8 ldfrag(const float* W, long row, int kb){
    const float4 v0 = *(const float4*)(W + row + kb);
    const float4 v1 = *(const float4*)(W + row + kb + 4);
    return mk8(pkrtz(v0.x,v0.y), pkrtz(v0.z,v0.w), pkrtz(v1.x,v1.y), pkrtz(v1.z,v1.w));
}
__device__ __forceinline__ f4 mfma16(h8 a, h8 b, f4 c){
    return __builtin_amdgcn_mfma_f32_16x16x32_f16(a,b,c,0,0,0);
}
__device__ __forceinline__ f4 relu4(f4 v){
    v[0]=fmaxf(v[0],0.f); v[1]=fmaxf(v[1],0.f); v[2]=fmaxf(v[2],0.f); v[3]=fmaxf(v[3],0.f); return v;
}
// intra-wave LDS write->read fence (in-order DS pipe + stop compiler reordering; rule #18)
__device__ __forceinline__ void wsync(){
    asm volatile("s_waitcnt lgkmcnt(0)" ::: "memory");
    __builtin_amdgcn_sched_barrier(0);
}

// store C-layout tile (acc[nt]: col=16nt+(lane&15), rows (lane>>4)*4+r) as swizzled f16 [16][64]
__device__ __forceinline__ void store_ct(unsigned short* base, const f4* acc, int lane){
    const int m0    = (lane>>4)*4;
    const int ceven = lane & 14;
    const bool odd  = lane & 1;
    #pragma unroll
    for (int nt = 0; nt < 4; ++nt){
        const int c0 = 16*nt + ceven;
        #pragma unroll
        for (int r = 0; r < 4; ++r){
            const float mine = acc[nt][r];
            const float oth  = __shfl_xor(mine, 1);
            if (!odd){
                const int m    = m0 + r;
                const int gp   = (c0 >> 3) ^ (m & 7);
                const int byte = m*128 + gp*16 + ((2*c0) & 15);
                *(unsigned*)((char*)base + byte) = h2u(pkrtz(mine, oth));
            }
        }
    }
}
__device__ __forceinline__ h8 read_af(const unsigned short* base, int lane, int kt){
    const int row  = lane & 15;
    const int gp   = (4*kt + (lane>>4)) ^ (row & 7);
    const int byte = row*128 + gp*16;
    return *(const h8*)((const char*)base + byte);
}

__global__ __launch_bounds__(512, 2)   // 256-VGPR budget: ~110-reg live set fits, NO scratch spill
void ue_v3(const int* __restrict__ nodes, const int* __restrict__ hitems,
           const int* __restrict__ hrat, const int* __restrict__ hlen,
           const float* __restrict__ u2e, const float* __restrict__ i2e,
           const float* __restrict__ r2e,
           const float* __restrict__ w1w, const float* __restrict__ w1b,
           const float* __restrict__ w2w, const float* __restrict__ w2b,
           const float* __restrict__ a1w, const float* __restrict__ a1b,
           const float* __restrict__ a2w, const float* __restrict__ a2b,
           const float* __restrict__ a3w, const float* __restrict__ a3b,
           float* __restrict__ out, int n_nodes)
{
    const int tid  = threadIdx.x;
    const int lane = tid & 63;
    const int wid  = tid >> 6;
    const int nidx = lane & 15;
    const int kgrp = lane >> 4;

    // weight fragments: 40 blocks (W1:0-15, W2:16-23, A1o:24-31, A2:32-39), each 64 lanes x 16B
    __shared__ __align__(16) unsigned short wlds[40*512];
    __shared__ __align__(16) unsigned short xfer[WPB][16*64];   // per-wave transpose buffer
    __shared__ __align__(16) float uax[WPB][64];
    __shared__ __align__(16) float ubl[WPB][64];
    __shared__ int ihs[WPB][HIST];
    __shared__ int rhs[WPB][HIST];

    // ---- cooperative weight staging (once per block) ----
    for (int f = tid; f < 40*64; f += blockDim.x) {
        const int blk = f >> 6, l = f & 63;
        const float* src; int ld, kt, nt;
        if (blk < 16)      { kt = blk>>2;      nt = blk&3;      src = w1w; ld = 128; }
        else if (blk < 24) { kt = (blk-16)>>2; nt = (blk-16)&3; src = w2w; ld = 64;  }
        else if (blk < 32) { kt = (blk-24)>>2; nt = (blk-24)&3; src = a1w; ld = 128; }
        else               { kt = (blk-32)>>2; nt = (blk-32)&3; src = a2w; ld = 64;  }
        const int nrow = 16*nt + (l & 15);
        const int kcol = 32*kt + 8*(l >> 4);
        *(h8*)&wlds[blk*512 + l*8] = ldfrag(src, (long)nrow*ld, kcol);
    }
    __syncthreads();   // the ONLY block-wide barrier

    #define BF(base,kt,nt) (*(const h8*)&wlds[((base)+(kt)*4+(nt))*512 + lane*8])

    float b1c[4], b2c[4], ab2c[4], a3c[4];
    #pragma unroll
    for (int nt = 0; nt < 4; ++nt){
        b1c[nt]  = w1b[16*nt + nidx];
        b2c[nt]  = w2b[16*nt + nidx];
        ab2c[nt] = a2b[16*nt + nidx];
        a3c[nt]  = a3w[16*nt + nidx];
    }
    const float ab1r = a1b[lane];
    const float NEG_INF = -__builtin_inff();

    for (int n = blockIdx.x * WPB + wid; n < n_nodes; n += gridDim.x * WPB) {
        const int node = nodes[n];
        const int hl   = hlen[n];

        uax[wid][lane] = u2e[(long)node * 64 + lane];
        if (lane < HIST){ ihs[wid][lane] = hitems[n*HIST+lane]; rhs[wid][lane] = hrat[n*HIST+lane]; }
        wsync();

        // ubias_j = ab1_j + sum_k u_k * A1[j][64+k]  (u-half of att1, folded per node)
        float u0 = ab1r, u1 = 0.f, u2 = 0.f, u3 = 0.f;
        #pragma unroll
        for (int t = 0; t < 16; ++t) {
            const float4 v = *(const float4*)(a1w + (long)lane*128 + 64 + 4*t);
            u0 = fmaf(v.x, uax[wid][4*t+0], u0);
            u1 = fmaf(v.y, uax[wid][4*t+1], u1);
            u2 = fmaf(v.z, uax[wid][4*t+2], u2);
            u3 = fmaf(v.w, uax[wid][4*t+3], u3);
        }
        ubl[wid][lane] = (u0 + u1) + (u2 + u3);
        wsync();
        float ubc[4];
        #pragma unroll
        for (int nt = 0; nt < 4; ++nt) ubc[nt] = ubl[wid][16*nt + nidx];

        // online softmax state
        float m_run = NEG_INF, run_sum = 0.f;
        float outacc[4] = {0.f, 0.f, 0.f, 0.f};

        const int tiles = (hl + 15) >> 4;
        for (int t = 0; t < tiles; ++t) {
            int p = t*16 + nidx; if (p >= hl) p = hl - 1;   // clamp pad rows (masked below)
            const long irow = (long)ihs[wid][p] * 64;
            const long rrow = (long)rhs[wid][p] * 64;
            const int  kb   = 8 * kgrp;
            const h8 Xf0 = ldfrag(i2e, irow, kb);
            const h8 Xf1 = ldfrag(i2e, irow, 32 + kb);
            const h8 Xf2 = ldfrag(r2e, rrow, kb);
            const h8 Xf3 = ldfrag(r2e, rrow, 32 + kb);

            // layer 1: [16x128] @ [128x64]
            f4 acc[4];
            #pragma unroll
            for (int nt = 0; nt < 4; ++nt){
                f4 c = { b1c[nt], b1c[nt], b1c[nt], b1c[nt] };
                c = mfma16(Xf0, BF(0,0,nt), c);
                c = mfma16(Xf1, BF(0,1,nt), c);
                c = mfma16(Xf2, BF(0,2,nt), c);
                c = mfma16(Xf3, BF(0,3,nt), c);
                acc[nt] = relu4(c);
            }
            store_ct(xfer[wid], acc, lane);
            wsync();
            const h8 yf0 = read_af(xfer[wid], lane, 0), yf1 = read_af(xfer[wid], lane, 1);

            // layer 2 -> o (stays in f32 C-layout regs)
            f4 occ[4];
            #pragma unroll
            for (int nt = 0; nt < 4; ++nt){
                f4 c = { b2c[nt], b2c[nt], b2c[nt], b2c[nt] };
                c = mfma16(yf0, BF(16,0,nt), c);
                c = mfma16(yf1, BF(16,1,nt), c);
                occ[nt] = relu4(c);
            }
            store_ct(xfer[wid], occ, lane);
            wsync();
            const h8 of0 = read_af(xfer[wid], lane, 0), of1 = read_af(xfer[wid], lane, 1);

            // att layer 1 (o-half; u folded in ubias)
            #pragma unroll
            for (int nt = 0; nt < 4; ++nt){
                f4 c = { ubc[nt], ubc[nt], ubc[nt], ubc[nt] };
                c = mfma16(of0, BF(24,0,nt), c);
                c = mfma16(of1, BF(24,1,nt), c);
                acc[nt] = relu4(c);
            }
            store_ct(xfer[wid], acc, lane);
            wsync();
            const h8 af0 = read_af(xfer[wid], lane, 0), af1 = read_af(xfer[wid], lane, 1);

            // att layer 2
            #pragma unroll
            for (int nt = 0; nt < 4; ++nt){
                f4 c = { ab2c[nt], ab2c[nt], ab2c[nt], ab2c[nt] };
                c = mfma16(af0, BF(32,0,nt), c);
                c = mfma16(af1, BF(32,1,nt), c);
                acc[nt] = relu4(c);
            }

            // scores per row (att3 bias dropped: softmax shift-invariant)
            float sv0 = 0.f, sv1 = 0.f, sv2 = 0.f, sv3 = 0.f;
            #pragma unroll
            for (int nt = 0; nt < 4; ++nt){
                sv0 = fmaf(acc[nt][0], a3c[nt], sv0);
                sv1 = fmaf(acc[nt][1], a3c[nt], sv1);
                sv2 = fmaf(acc[nt][2], a3c[nt], sv2);
                sv3 = fmaf(acc[nt][3], a3c[nt], sv3);
            }
            #pragma unroll
            for (int off = 1; off <= 8; off <<= 1){
                sv0 += __shfl_xor(sv0, off);
                sv1 += __shfl_xor(sv1, off);
                sv2 += __shfl_xor(sv2, off);
                sv3 += __shfl_xor(sv3, off);
            }

            // online softmax update over this tile's 16 rows
            const int base = t*16 + kgrp*4;
            const bool v0 = base+0 < hl, v1 = base+1 < hl, v2 = base+2 < hl, v3 = base+3 < hl;
            float tmax = fmaxf(fmaxf(v0 ? sv0 : NEG_INF, v1 ? sv1 : NEG_INF),
                               fmaxf(v2 ? sv2 : NEG_INF, v3 ? sv3 : NEG_INF));
            tmax = fmaxf(tmax, __shfl_xor(tmax, 16));
            tmax = fmaxf(tmax, __shfl_xor(tmax, 32));
            const float m_new = fmaxf(m_run, tmax);
            const float fs = expf(m_run - m_new);    // 0 on first tile (m_run=-inf)
            const float w0 = v0 ? expf(sv0 - m_new) : 0.f;
            const float w1 = v1 ? expf(sv1 - m_new) : 0.f;
            const float w2 = v2 ? expf(sv2 - m_new) : 0.f;
            const float w3 = v3 ? expf(sv3 - m_new) : 0.f;
            float wsum = (w0 + w1) + (w2 + w3);
            float cp[4];
            #pragma unroll
            for (int nt = 0; nt < 4; ++nt)
                cp[nt] = ((w0*occ[nt][0] + w1*occ[nt][1]) + (w2*occ[nt][2] + w3*occ[nt][3]));
            wsum += __shfl_xor(wsum, 16); wsum += __shfl_xor(wsum, 32);
            #pragma unroll
            for (int nt = 0; nt < 4; ++nt){
                cp[nt] += __shfl_xor(cp[nt], 16);
                cp[nt] += __shfl_xor(cp[nt], 32);
            }
            run_sum = run_sum * fs + wsum;
            #pragma unroll
            for (int nt = 0; nt < 4; ++nt) outacc[nt] = outacc[nt] * fs + cp[nt];
            m_run = m_new;
        }

        const float inv = 1.f / run_sum;
        if (kgrp == 0){
            #pragma unroll
            for (int nt = 0; nt < 4; ++nt)
                out[(long)n * 64 + 16*nt + nidx] = outacc[nt] * inv;
        }
    }
    #undef BF
}

extern "C" void kernel_launch(void* const* d_in, const int* in_sizes, int n_in,
                              void* d_out, int out_size, void* d_ws, size_t ws_size,
                              hipStream_t stream) {
    const int*   nodes  = (const int*)d_in[0];
    const int*   hitems = (const int*)d_in[1];
    const int*   hrat   = (const int*)d_in[2];
    const int*   hlenp  = (const int*)d_in[3];
    const float* u2e    = (const float*)d_in[4];
    const float* i2e    = (const float*)d_in[5];
    const float* r2e    = (const float*)d_in[6];
    const float* w1w    = (const float*)d_in[7];
    const float* w1b    = (const float*)d_in[8];
    const float* w2w    = (const float*)d_in[9];
    const float* w2b    = (const float*)d_in[10];
    const float* a1w    = (const float*)d_in[11];
    const float* a1b    = (const float*)d_in[12];
    const float* a2w    = (const float*)d_in[13];
    const float* a2b    = (const float*)d_in[14];
    const float* a3w    = (const float*)d_in[15];
    const float* a3b    = (const float*)d_in[16];
    float* out = (float*)d_out;

    const int n_nodes = in_sizes[0];
    const int blocks  = 2048;   // 8 waves each: one node per wave, grid covers 16384 exactly
    ue_v3<<<dim3(blocks), dim3(512), 0, stream>>>(
        nodes, hitems, hrat, hlenp, u2e, i2e, r2e,
        w1w, w1b, w2w, w2b, a1w, a1b, a2w, a2b, a3w, a3b,
        out, n_nodes);
}